// Round 1
// baseline (294.656 us; speedup 1.0000x reference)
//
#include <hip/hip_runtime.h>

// VQ-VAE vector quantizer, MI355X (gfx950).
// B=64, C=D=64, H=32, W=32 -> N=65536 tokens, K=1024 codes.
// Outputs (flat, concatenated): z_q [4194304] f32 NCHW, loss [1], perplexity [1].
//
// Exact fp32 distances (same expansion as reference) to preserve argmin
// semantics; codebook rows are wave-uniform -> SMEM (s_load) broadcast,
// inner loop is pure v_fmac_f32 with SGPR operand.

#define BB    64
#define DD    64
#define HH    32
#define WW    32
#define HW    (HH * WW)      // 1024
#define NTOK  (BB * HW)      // 65536
#define KK    1024
#define KCHUNK 256
#define NCHUNK (KK / KCHUNK) // 4
#define NELEM (BB * DD * HW) // 4194304

// ---- workspace layout (bytes) ----
// [0, 524288)        : u64 packed[NTOK]  (sortable distbits<<32 | idx), memset 0xFF
// [524288, 528384)   : f32 c2[KK]
// [528384, 532480)   : i32 hist[KK]                                  , memset 0
// [532480, 532736)   : f32 loss_part[64]                             , memset 0
#define WS_PACKED   0
#define WS_C2       524288
#define WS_HIST     528384
#define WS_LOSSP    532480

__global__ __launch_bounds__(256) void c2_kernel(const float* __restrict__ cb,
                                                 float* __restrict__ c2) {
    int k = blockIdx.x * 256 + threadIdx.x;
    if (k >= KK) return;
    const float* cp = cb + k * DD;
    float s0 = 0.f, s1 = 0.f, s2 = 0.f, s3 = 0.f;
#pragma unroll
    for (int d = 0; d < DD; d += 4) {
        s0 = fmaf(cp[d + 0], cp[d + 0], s0);
        s1 = fmaf(cp[d + 1], cp[d + 1], s1);
        s2 = fmaf(cp[d + 2], cp[d + 2], s2);
        s3 = fmaf(cp[d + 3], cp[d + 3], s3);
    }
    c2[k] = (s0 + s1) + (s2 + s3);
}

__global__ __launch_bounds__(256, 4) void argmin_kernel(
    const float* __restrict__ z, const float* __restrict__ cb,
    const float* __restrict__ c2, unsigned long long* __restrict__ packed) {
    int n  = blockIdx.x * 256 + threadIdx.x;   // token
    int b  = n >> 10;
    int hw = n & (HW - 1);
    const float* zp = z + (size_t)b * (DD * HW) + hw;

    // strided (stride = HW floats) but wave-coalesced load of this token's 64 dims
    float zr[DD];
#pragma unroll
    for (int d = 0; d < DD; d++) zr[d] = zp[d * HW];

    float z2 = 0.f;
#pragma unroll
    for (int d = 0; d < DD; d++) z2 = fmaf(zr[d], zr[d], z2);

    int   k0    = blockIdx.y * KCHUNK;
    float bestd = __builtin_inff();
    int   besti = k0;

    for (int k = k0; k < k0 + KCHUNK; ++k) {
        const float* cp = cb + k * DD;   // wave-uniform address -> s_load broadcast
        float a0 = 0.f, a1 = 0.f, a2 = 0.f, a3 = 0.f;
#pragma unroll
        for (int d = 0; d < DD; d += 4) {
            a0 = fmaf(zr[d + 0], cp[d + 0], a0);
            a1 = fmaf(zr[d + 1], cp[d + 1], a1);
            a2 = fmaf(zr[d + 2], cp[d + 2], a2);
            a3 = fmaf(zr[d + 3], cp[d + 3], a3);
        }
        float dot = (a0 + a1) + (a2 + a3);
        float d2  = (z2 + c2[k]) - 2.0f * dot;   // same expansion as reference
        if (d2 < bestd) { bestd = d2; besti = k; }
    }

    // order-preserving float->uint map (handles tiny negative d2 from rounding)
    unsigned int bits = __float_as_uint(bestd);
    bits = (bits & 0x80000000u) ? ~bits : (bits | 0x80000000u);
    unsigned long long key =
        ((unsigned long long)bits << 32) | (unsigned long long)(unsigned int)besti;
    atomicMin(&packed[n], key);   // ties across chunks -> smaller idx wins
}

__global__ __launch_bounds__(256) void output_kernel(
    const float* __restrict__ z, const float* __restrict__ cb,
    const unsigned long long* __restrict__ packed, float* __restrict__ out,
    float* __restrict__ loss_part, int* __restrict__ hist) {
    int e  = blockIdx.x * 256 + threadIdx.x;   // NCHW linear index
    int hw = e & (HW - 1);
    int t  = e >> 10;          // b*64 + c
    int c  = t & (DD - 1);
    int b  = t >> 6;
    int n  = b * HW + hw;

    int   idx  = (int)(unsigned int)(packed[n] & 0xFFFFFFFFull);
    float zv   = z[e];
    float q    = cb[idx * DD + c];
    float diff = q - zv;                 // (z_q - z)
    out[e]     = zv + diff;              // straight-through: z + (z_q - z)

    float sq = diff * diff;
#pragma unroll
    for (int off = 32; off > 0; off >>= 1) sq += __shfl_down(sq, off);

    __shared__ float lred[4];
    if ((threadIdx.x & 63) == 0) lred[threadIdx.x >> 6] = sq;
    __syncthreads();
    if (threadIdx.x == 0) {
        float v = (lred[0] + lred[1]) + (lred[2] + lred[3]);
        atomicAdd(&loss_part[blockIdx.x & 63], v);  // spread contention over 64 slots
    }
    // c is wave-uniform (lanes vary hw only): one count per token
    if (c == 0) atomicAdd(&hist[idx], 1);
}

__global__ __launch_bounds__(1024) void finalize_kernel(
    const int* __restrict__ hist, const float* __restrict__ loss_part,
    const int* __restrict__ flg, float* __restrict__ out) {
    __shared__ float red[16];
    int   k = threadIdx.x;
    float e = (float)hist[k] * (1.0f / 65536.0f);   // exact (pow2 divide)
    float v = e * logf(e + 1e-10f);
#pragma unroll
    for (int off = 32; off > 0; off >>= 1) v += __shfl_down(v, off);
    if ((k & 63) == 0) red[k >> 6] = v;
    __syncthreads();
    if (k == 0) {
        float s = 0.f;
#pragma unroll
        for (int i = 0; i < 16; i++) s += red[i];
        out[NELEM + 1] = expf(-s);                  // perplexity

        float ls = 0.f;
        for (int i = 0; i < 64; i++) ls += loss_part[i];
        float m    = ls * (1.0f / (float)NELEM);    // mean((z_q - z)^2), exact pow2 div
        out[NELEM] = (*flg) ? (0.25f * m + m) : 0.0f;  // BETA*mean + mean
    }
}

extern "C" void kernel_launch(void* const* d_in, const int* in_sizes, int n_in,
                              void* d_out, int out_size, void* d_ws, size_t ws_size,
                              hipStream_t stream) {
    const float* z   = (const float*)d_in[0];   // (64,64,32,32) f32 NCHW
    const float* cb  = (const float*)d_in[1];   // (1024,64) f32
    /* d_in[2] codebook_weight: unused by reference */
    const int*   flg = (const int*)d_in[3];     // flg_train

    float* out = (float*)d_out;
    char*  ws  = (char*)d_ws;

    unsigned long long* packed    = (unsigned long long*)(ws + WS_PACKED);
    float*              c2        = (float*)(ws + WS_C2);
    int*                hist      = (int*)(ws + WS_HIST);
    float*              loss_part = (float*)(ws + WS_LOSSP);

    hipMemsetAsync(packed, 0xFF, NTOK * sizeof(unsigned long long), stream); // u64 max
    hipMemsetAsync(ws + WS_HIST, 0, KK * sizeof(int) + 64 * sizeof(float), stream);

    c2_kernel<<<KK / 256, 256, 0, stream>>>(cb, c2);
    argmin_kernel<<<dim3(NTOK / 256, NCHUNK), 256, 0, stream>>>(z, cb, c2, packed);
    output_kernel<<<NELEM / 256, 256, 0, stream>>>(z, cb, packed, out, loss_part, hist);
    finalize_kernel<<<1, 1024, 0, stream>>>(hist, loss_part, flg, out);
}

// Round 2
// 145.453 us; speedup vs baseline: 2.0258x; 2.0258x over previous
//
#include <hip/hip_runtime.h>

// VQ-VAE quantizer, MI355X (gfx950). B=64, C=D=64, H=32, W=32 -> N=65536 tokens, K=1024 codes.
// Round 2: MFMA argmin via split-fp32->bf16 (hi/lo), 4 cross-product passes, fp32 accumulate.
//   argmin d2 == argmax (dot - c2/2): c2 folded into MFMA accumulator init.
//   Codebook pre-packed in B-fragment order; A-frags live in VGPRs; k-loop has no LDS/barrier.
//   Fused: argmin + codebook gather + straight-through output + loss + histogram in one kernel.
// Outputs (flat): z_q [4194304] f32 NCHW, loss [1], perplexity [1].

typedef __attribute__((ext_vector_type(8))) short short8;   // 8 bf16 (4 VGPRs)
typedef __attribute__((ext_vector_type(4))) float float4v;  // MFMA C/D frag

#define KK     1024
#define DD     64
#define NTOK   65536
#define NELEM  4194304
#define MTILE  128
#define NBLK   (NTOK / MTILE)   // 512

// ---- workspace layout (bytes) ----
#define WS_CBF   0        // ushort[131072]: packed split-bf16 codebook, B-frag order (262144 B)
#define WS_C2H   262144   // f32 c2h[1024] = -0.5*||c||^2
#define WS_HIST  266240   // i32 hist[1024]
#define WS_LOSS  270336   // f32 loss_part[64]

__device__ __forceinline__ unsigned bf16_rne(float x) {
    unsigned u = __float_as_uint(x);
    return (u + 0x7fffu + ((u >> 16) & 1u)) >> 16;
}

// 64 blocks x 256: thread g handles code n=g>>4, dims (g&15)*4..+3.
// Packs cbf[chunk][fid][lane][8] with fid = split*2 + step; lane = kquad*16 + (n&15).
// Also writes c2h and zeroes hist/loss_part.
__global__ __launch_bounds__(256) void prep_kernel(
    const float* __restrict__ cb, ushort* __restrict__ cbf,
    float* __restrict__ c2h, int* __restrict__ hist, float* __restrict__ loss_part) {
    int tid = threadIdx.x;
    int gid = blockIdx.x * 256 + tid;        // 0..16383
    if (gid < KK) hist[gid] = 0;
    if (gid < 64) loss_part[gid] = 0.f;

    int n  = gid >> 4;                       // code
    int dg = (gid & 15) * 4;                 // first dim of this thread's group
    const float* cp = cb + n * DD + dg;
    float4v v = *(const float4v*)cp;         // 16B-aligned
    float s = v.x * v.x + v.y * v.y + v.z * v.z + v.w * v.w;
    s += __shfl_xor(s, 1); s += __shfl_xor(s, 2);
    s += __shfl_xor(s, 4); s += __shfl_xor(s, 8);
    if ((gid & 15) == 0) c2h[n] = -0.5f * s;

    int c = n >> 4, col = n & 15;
#pragma unroll
    for (int jj = 0; jj < 4; jj++) {
        int d = dg + jj;
        float x = ((const float*)cp)[jj];
        unsigned hb = bf16_rne(x);
        float hf = __uint_as_float(hb << 16);
        unsigned lb = bf16_rne(x - hf);
        int st = d >> 5, kq = (d & 31) >> 3, j = d & 7;
        int lane = kq * 16 + col;
        cbf[((c * 4 + 0 * 2 + st) * 64 + lane) * 8 + j] = (ushort)hb;  // hi split
        cbf[((c * 4 + 1 * 2 + st) * 64 + lane) * 8 + j] = (ushort)lb;  // lo split
    }
}

// 512 blocks x 256 threads (4 waves). Block = 128 tokens; wave = 2 groups of 16 tokens.
// k-loop: 64 chunks of 16 codes; per chunk 16 MFMA (2 groups x 2 K-steps x 4 split products).
__global__ __launch_bounds__(256, 4) void vq_kernel(
    const float* __restrict__ z, const float* __restrict__ cb,
    const ushort* __restrict__ cbf, const float* __restrict__ c2h,
    float* __restrict__ out, float* __restrict__ loss_part, int* __restrict__ hist) {
    __shared__ int   s_idx[MTILE];
    __shared__ float s_q[MTILE * 65];        // +1 dword pad: conflict-free both phases
    __shared__ float s_red[4];

    int tid  = threadIdx.x;
    int lane = tid & 63, wave = tid >> 6;
    int quad = lane >> 4, col = lane & 15;
    int tokbase = blockIdx.x * MTILE;
    int b = tokbase >> 10, hwb = tokbase & 1023;
    const float* zb = z + b * 65536 + hwb;   // base of this block's (b, *, hw-window)

    // ---- A fragments: 2 token-groups x {hi,lo} x 2 K-steps, once per tile ----
    short8 ah[2][2], al[2][2];
#pragma unroll
    for (int g = 0; g < 2; g++) {
        int rel = wave * 32 + g * 16 + col;  // token within tile (A row m = lane&15)
#pragma unroll
        for (int st = 0; st < 2; st++) {
            short8 h8, l8;
#pragma unroll
            for (int j = 0; j < 8; j++) {
                int d = st * 32 + quad * 8 + j;
                float x = zb[d * 1024 + rel];          // 16-lane coalesced per (d)
                unsigned hb = bf16_rne(x);
                float hf = __uint_as_float(hb << 16);
                unsigned lb = bf16_rne(x - hf);
                h8[j] = (short)hb; l8[j] = (short)lb;
            }
            ah[g][st] = h8; al[g][st] = l8;
        }
    }

    float best[2][4]; int bidx[2][4];
#pragma unroll
    for (int g = 0; g < 2; g++)
#pragma unroll
        for (int r = 0; r < 4; r++) { best[g][r] = -1e38f; bidx[g][r] = 0; }

    // ---- k-loop over 64 code-chunks: no LDS, no barriers ----
    for (int c = 0; c < 64; c++) {
        float ini = c2h[c * 16 + col];                 // -0.5*c2 of this lane's code
        const ushort* cp = cbf + c * 2048;             // 4KB chunk, lane-contiguous frags
        short8 bh0 = *(const short8*)(cp + (0 * 64 + lane) * 8);
        short8 bh1 = *(const short8*)(cp + (1 * 64 + lane) * 8);
        short8 bl0 = *(const short8*)(cp + (2 * 64 + lane) * 8);
        short8 bl1 = *(const short8*)(cp + (3 * 64 + lane) * 8);
        int code = c * 16 + col;
#pragma unroll
        for (int g = 0; g < 2; g++) {
            float4v a0 = {ini, ini, ini, ini};         // score = dot - c2/2 (argmax)
            float4v a1 = {0.f, 0.f, 0.f, 0.f};
            a0 = __builtin_amdgcn_mfma_f32_16x16x32_bf16(ah[g][0], bh0, a0, 0, 0, 0);
            a1 = __builtin_amdgcn_mfma_f32_16x16x32_bf16(ah[g][1], bh1, a1, 0, 0, 0);
            a0 = __builtin_amdgcn_mfma_f32_16x16x32_bf16(ah[g][0], bl0, a0, 0, 0, 0);
            a1 = __builtin_amdgcn_mfma_f32_16x16x32_bf16(ah[g][1], bl1, a1, 0, 0, 0);
            a0 = __builtin_amdgcn_mfma_f32_16x16x32_bf16(al[g][0], bh0, a0, 0, 0, 0);
            a1 = __builtin_amdgcn_mfma_f32_16x16x32_bf16(al[g][1], bh1, a1, 0, 0, 0);
            a0 = __builtin_amdgcn_mfma_f32_16x16x32_bf16(al[g][0], bl0, a0, 0, 0, 0);
            a1 = __builtin_amdgcn_mfma_f32_16x16x32_bf16(al[g][1], bl1, a1, 0, 0, 0);
#pragma unroll
            for (int r = 0; r < 4; r++) {
                float s = a0[r] + a1[r];
                if (s > best[g][r]) { best[g][r] = s; bidx[g][r] = code; }  // strict >: first-min ties
            }
        }
    }

    // ---- cross-lane argmax within each quad (16 lanes share 4 token-rows) ----
#pragma unroll
    for (int g = 0; g < 2; g++) {
#pragma unroll
        for (int r = 0; r < 4; r++) {
            float s = best[g][r]; int ix = bidx[g][r];
#pragma unroll
            for (int m = 1; m <= 8; m <<= 1) {
                float so = __shfl_xor(s, m);
                int   io = __shfl_xor(ix, m);
                if (so > s || (so == s && io < ix)) { s = so; ix = io; }
            }
            if (col == 0) {
                int t = wave * 32 + g * 16 + quad * 4 + r;   // C row = quad*4+reg
                s_idx[t] = ix;
                atomicAdd(&hist[ix], 1);                     // one per token
            }
        }
    }
    __syncthreads();

    // ---- gather selected code rows to LDS (coalesced 64-dword rows) ----
#pragma unroll
    for (int p = 0; p < 32; p++) {
        int i = p * 256 + tid;
        int t = i >> 6, d = i & 63;                          // t wave-uniform
        s_q[t * 65 + d] = cb[s_idx[t] * 64 + d];
    }
    __syncthreads();

    // ---- straight-through output + loss (coalesced 128-float runs per dim) ----
    float ls = 0.f;
#pragma unroll 4
    for (int p = 0; p < 32; p++) {
        int i = p * 256 + tid;
        int d = i >> 7, t = i & 127;
        int a = d * 1024 + t;
        float zv = zb[a];
        float q  = s_q[t * 65 + d];                          // bank = (t+d)%32: conflict-free
        float df = q - zv;
        out[b * 65536 + hwb + a] = zv + df;                  // z + (z_q - z), same expr as ref
        ls = fmaf(df, df, ls);
    }
#pragma unroll
    for (int off = 32; off; off >>= 1) ls += __shfl_down(ls, off);
    if (lane == 0) s_red[wave] = ls;
    __syncthreads();
    if (tid == 0) {
        float v = (s_red[0] + s_red[1]) + (s_red[2] + s_red[3]);
        atomicAdd(&loss_part[blockIdx.x & 63], v);
    }
}

__global__ __launch_bounds__(1024) void finalize_kernel(
    const int* __restrict__ hist, const float* __restrict__ loss_part,
    const int* __restrict__ flg, float* __restrict__ out) {
    __shared__ float red[16];
    int   k = threadIdx.x;
    float e = (float)hist[k] * (1.0f / 65536.0f);
    float v = e * logf(e + 1e-10f);
#pragma unroll
    for (int off = 32; off; off >>= 1) v += __shfl_down(v, off);
    if ((k & 63) == 0) red[k >> 6] = v;
    __syncthreads();
    if (k == 0) {
        float s = 0.f;
#pragma unroll
        for (int i = 0; i < 16; i++) s += red[i];
        out[NELEM + 1] = expf(-s);                           // perplexity

        float ls = 0.f;
        for (int i = 0; i < 64; i++) ls += loss_part[i];
        float m    = ls * (1.0f / (float)NELEM);
        out[NELEM] = (*flg) ? (0.25f * m + m) : 0.0f;        // BETA*mean + mean
    }
}

extern "C" void kernel_launch(void* const* d_in, const int* in_sizes, int n_in,
                              void* d_out, int out_size, void* d_ws, size_t ws_size,
                              hipStream_t stream) {
    const float* z   = (const float*)d_in[0];   // (64,64,32,32) f32 NCHW
    const float* cb  = (const float*)d_in[1];   // (1024,64) f32
    const int*   flg = (const int*)d_in[3];     // flg_train

    float* out = (float*)d_out;
    char*  ws  = (char*)d_ws;

    ushort* cbf       = (ushort*)(ws + WS_CBF);
    float*  c2h       = (float*)(ws + WS_C2H);
    int*    hist      = (int*)(ws + WS_HIST);
    float*  loss_part = (float*)(ws + WS_LOSS);

    prep_kernel<<<64, 256, 0, stream>>>(cb, cbf, c2h, hist, loss_part);
    vq_kernel<<<NBLK, 256, 0, stream>>>(z, cb, cbf, c2h, out, loss_part, hist);
    finalize_kernel<<<1, 1024, 0, stream>>>(hist, loss_part, flg, out);
}

// Round 4
// 122.443 us; speedup vs baseline: 2.4065x; 1.1879x over previous
//
#include <hip/hip_runtime.h>

// VQ-VAE quantizer, MI355X (gfx950). B=64, C=D=64, H=32, W=32 -> N=65536 tokens, K=1024 codes.
// Round 4: 3 plain dispatches (cooperative launch failed to execute in R3).
//   prep: pack split-bf16 codebook into B-fragment order, ONE contiguous 16B store/thread
//         (R2's 2-byte scatter stores were the ~50us overhead), + c2, + zero hist/loss.
//   vq:   exact split-fp32->bf16 4-product MFMA distances (absmax 0.0 in R2).
//         K split across wave pairs -> 1024 blocks = 4 waves/SIMD; register double-buffered
//         B-fragment prefetch; argmin d2 == argmax(dot - c2/2), c2 in accumulator init.
//   finalize: entropy -> perplexity, loss.
// Outputs (flat): z_q [4194304] f32 NCHW, loss [1], perplexity [1].

typedef __attribute__((ext_vector_type(8))) short short8;   // 8 bf16 (4 VGPRs)
typedef __attribute__((ext_vector_type(4))) float float4v;  // MFMA C/D frag

#define NELEM 4194304

// ---- workspace layout (bytes) ----
#define WS_CBF   0        // ushort[131072]: packed split-bf16 codebook, B-frag order (256 KB)
#define WS_C2H   262144   // f32 c2h[1024] = -0.5*||c||^2
#define WS_HIST  266240   // i32 hist[1024]
#define WS_LOSS  270336   // f32 loss_part[64]

__device__ __forceinline__ unsigned bf16_rne(float x) {
    unsigned u = __float_as_uint(x);
    return (u + 0x7fffu + ((u >> 16) & 1u)) >> 16;
}

// grid = 68 blocks x 256. Blocks 0..63: pack chunk bx (thread (fid=wave, lane) -> one
// contiguous 16B fragment) + c2. Blocks 64..67: zero hist; block 64 zeroes loss_part.
// Fragment layout: cbf[((chunk*4 + fid)*64 + lane)*8 + j], fid = split*2 + st,
// lane = kq*16 + col, code = chunk*16+col, dims d = st*32 + kq*8 + j.
__global__ __launch_bounds__(256) void prep_kernel(
    const float* __restrict__ cb, ushort* __restrict__ cbf,
    float* __restrict__ c2h, int* __restrict__ hist, float* __restrict__ loss_part) {
    __shared__ float s_c2[2][16];
    int tid  = threadIdx.x;
    int lane = tid & 63, wave = tid >> 6;
    int quad = lane >> 4, col = lane & 15;
    int bx   = blockIdx.x;

    if (bx >= 64) {
        hist[(bx - 64) * 256 + tid] = 0;
        if (bx == 64 && tid < 64) loss_part[tid] = 0.f;
        return;
    }
    int c = bx, fid = wave;
    int st = fid & 1, split = fid >> 1;
    int code  = c * 16 + col;
    int dbase = st * 32 + quad * 8;
    const float* cp = cb + code * 64 + dbase;
    float4v v0 = *(const float4v*)cp;
    float4v v1 = *(const float4v*)(cp + 4);
    float xs[8] = {v0.x, v0.y, v0.z, v0.w, v1.x, v1.y, v1.z, v1.w};
    short8 frag;
    float ssq = 0.f;
#pragma unroll
    for (int j = 0; j < 8; j++) {
        float x = xs[j];
        ssq = fmaf(x, x, ssq);
        unsigned hb = bf16_rne(x);
        if (split == 0) frag[j] = (short)hb;
        else            frag[j] = (short)bf16_rne(x - __uint_as_float(hb << 16));
    }
    *(short8*)(cbf + ((c * 4 + fid) * 64 + lane) * 8) = frag;   // contiguous 16B store
    if (split == 0) {                    // c2 from exact f32, deterministic order
        ssq += __shfl_xor(ssq, 16);      // sum over kq (lane bits 4..5)
        ssq += __shfl_xor(ssq, 32);
        if (quad == 0) s_c2[st][col] = ssq;
    }
    __syncthreads();
    if (tid < 16) c2h[c * 16 + tid] = -0.5f * (s_c2[0][tid] + s_c2[1][tid]);
}

// grid = 1024 blocks x 256 (4 waves = 4 blocks/CU = 4 waves/SIMD). Block = 64 tokens.
// wave: tokhalf = wave&1 (32 tokens), khalf = wave>>1 (chunks khalf*32 .. +31).
__global__ __launch_bounds__(256, 4) void vq_kernel(
    const float* __restrict__ z, const float* __restrict__ cb,
    const ushort* __restrict__ cbf, const float* __restrict__ c2h,
    float* __restrict__ out, float* __restrict__ loss_part, int* __restrict__ hist)
{
    __shared__ float s_q[64 * 65];       // gathered code rows, +1 pad (16.6 KB)
    __shared__ float s_ms[2][64];        // K-half merge: score
    __shared__ int   s_mi[2][64];        // K-half merge: index
    __shared__ int   s_idx[64];
    __shared__ float s_red[4];

    int tid  = threadIdx.x;
    int lane = tid & 63, wave = tid >> 6;
    int quad = lane >> 4, col = lane & 15;
    int bx   = blockIdx.x;

    int tokbase = bx * 64;
    int bb = tokbase >> 10, hwb = tokbase & 1023;
    const float* zb = z + bb * 65536 + hwb;
    int tokhalf = wave & 1, khalf = wave >> 1;

    // A-fragments: 2 groups x {hi,lo} x 2 K-steps, loaded once
    short8 ah[2][2], al[2][2];
#pragma unroll
    for (int g = 0; g < 2; g++) {
        int rel = tokhalf * 32 + g * 16 + col;       // token row m = lane&15
#pragma unroll
        for (int st = 0; st < 2; st++) {
            short8 h8, l8;
#pragma unroll
            for (int j = 0; j < 8; j++) {
                int d = st * 32 + quad * 8 + j;      // k = quad*8+j
                float x = zb[d * 1024 + rel];
                unsigned hb = bf16_rne(x);
                h8[j] = (short)hb;
                l8[j] = (short)bf16_rne(x - __uint_as_float(hb << 16));
            }
            ah[g][st] = h8; al[g][st] = l8;
        }
    }

    float best[2][4]; int bidx[2][4];
#pragma unroll
    for (int g = 0; g < 2; g++)
#pragma unroll
        for (int r = 0; r < 4; r++) { best[g][r] = -1e38f; bidx[g][r] = 0; }

    // k-loop: 32 chunks, register double-buffered B-frag prefetch, no barriers
    int cbase = khalf * 32;
    const ushort* cw = cbf + lane * 8;
    {
        const ushort* p0 = cw + cbase * 2048;
        short8 nb0 = *(const short8*)(p0 + 0);
        short8 nb1 = *(const short8*)(p0 + 512);
        short8 nb2 = *(const short8*)(p0 + 1024);
        short8 nb3 = *(const short8*)(p0 + 1536);
        float  nini = c2h[cbase * 16 + col];
        for (int cc = 0; cc < 32; cc++) {
            short8 bh0 = nb0, bh1 = nb1, bl0 = nb2, bl1 = nb3;
            float  ini = nini;
            if (cc < 31) {                            // prefetch next chunk
                const ushort* np = cw + (cbase + cc + 1) * 2048;
                nb0 = *(const short8*)(np + 0);
                nb1 = *(const short8*)(np + 512);
                nb2 = *(const short8*)(np + 1024);
                nb3 = *(const short8*)(np + 1536);
                nini = c2h[(cbase + cc + 1) * 16 + col];
            }
            int code = (cbase + cc) * 16 + col;
#pragma unroll
            for (int g = 0; g < 2; g++) {
                float4v a0 = {ini, ini, ini, ini};    // score = dot - c2/2 (argmax)
                float4v a1 = {0.f, 0.f, 0.f, 0.f};
                a0 = __builtin_amdgcn_mfma_f32_16x16x32_bf16(ah[g][0], bh0, a0, 0, 0, 0);
                a1 = __builtin_amdgcn_mfma_f32_16x16x32_bf16(ah[g][1], bh1, a1, 0, 0, 0);
                a0 = __builtin_amdgcn_mfma_f32_16x16x32_bf16(ah[g][0], bl0, a0, 0, 0, 0);
                a1 = __builtin_amdgcn_mfma_f32_16x16x32_bf16(ah[g][1], bl1, a1, 0, 0, 0);
                a0 = __builtin_amdgcn_mfma_f32_16x16x32_bf16(al[g][0], bh0, a0, 0, 0, 0);
                a1 = __builtin_amdgcn_mfma_f32_16x16x32_bf16(al[g][1], bh1, a1, 0, 0, 0);
                a0 = __builtin_amdgcn_mfma_f32_16x16x32_bf16(al[g][0], bl0, a0, 0, 0, 0);
                a1 = __builtin_amdgcn_mfma_f32_16x16x32_bf16(al[g][1], bl1, a1, 0, 0, 0);
#pragma unroll
                for (int r = 0; r < 4; r++) {
                    float s = a0[r] + a1[r];
                    if (s > best[g][r]) { best[g][r] = s; bidx[g][r] = code; }  // strict >: first-min
                }
            }
        }
    }

    // quad-reduction (C row = quad*4+r, col = code lane)
#pragma unroll
    for (int g = 0; g < 2; g++) {
#pragma unroll
        for (int r = 0; r < 4; r++) {
            float s = best[g][r]; int ix = bidx[g][r];
#pragma unroll
            for (int m = 1; m <= 8; m <<= 1) {
                float so = __shfl_xor(s, m);
                int   io = __shfl_xor(ix, m);
                if (so > s || (so == s && io < ix)) { s = so; ix = io; }
            }
            if (col == 0) {
                int t = tokhalf * 32 + g * 16 + quad * 4 + r;
                s_ms[khalf][t] = s; s_mi[khalf][t] = ix;
            }
        }
    }
    __syncthreads();

    // merge K-halves (half0 codes < half1 codes: tie -> half0 = first-min)
    if (tid < 64) {
        float s0 = s_ms[0][tid], s1 = s_ms[1][tid];
        int   i0 = s_mi[0][tid], i1 = s_mi[1][tid];
        int   ix = (s1 > s0) ? i1 : i0;
        s_idx[tid] = ix;
        atomicAdd(&hist[ix], 1);                       // one per token
    }
    __syncthreads();

    // gather selected code rows (wave-uniform row, 256B coalesced)
#pragma unroll
    for (int p = 0; p < 16; p++) {
        int i = p * 256 + tid;
        int t = i >> 6, d = i & 63;
        s_q[t * 65 + d] = cb[s_idx[t] * 64 + d];
    }
    __syncthreads();

    // straight-through output + loss (256B contiguous runs per wave)
    float ls = 0.f;
#pragma unroll 4
    for (int p = 0; p < 16; p++) {
        int i = p * 256 + tid;
        int d = i >> 6, t = i & 63;
        int a = d * 1024 + t;
        float zv = zb[a];
        float q  = s_q[t * 65 + d];                    // bank(t*65+d)=t+d: conflict-free
        float df = q - zv;
        out[bb * 65536 + hwb + a] = zv + df;           // z + (z_q - z)
        ls = fmaf(df, df, ls);
    }
#pragma unroll
    for (int off = 32; off; off >>= 1) ls += __shfl_down(ls, off);
    if (lane == 0) s_red[wave] = ls;
    __syncthreads();
    if (tid == 0) {
        float v = (s_red[0] + s_red[1]) + (s_red[2] + s_red[3]);
        atomicAdd(&loss_part[bx & 63], v);
    }
}

__global__ __launch_bounds__(1024) void finalize_kernel(
    const int* __restrict__ hist, const float* __restrict__ loss_part,
    const int* __restrict__ flg, float* __restrict__ out) {
    __shared__ float red[16];
    int   k = threadIdx.x;
    float e = (float)hist[k] * (1.0f / 65536.0f);
    float v = e * logf(e + 1e-10f);
#pragma unroll
    for (int off = 32; off; off >>= 1) v += __shfl_down(v, off);
    if ((k & 63) == 0) red[k >> 6] = v;
    __syncthreads();
    if (k == 0) {
        float s = 0.f;
#pragma unroll
        for (int i = 0; i < 16; i++) s += red[i];
        out[NELEM + 1] = expf(-s);                     // perplexity

        float ls = 0.f;
        for (int i = 0; i < 64; i++) ls += loss_part[i];
        float m    = ls * (1.0f / (float)NELEM);
        out[NELEM] = (*flg) ? (0.25f * m + m) : 0.0f;  // BETA*mean + mean
    }
}

extern "C" void kernel_launch(void* const* d_in, const int* in_sizes, int n_in,
                              void* d_out, int out_size, void* d_ws, size_t ws_size,
                              hipStream_t stream) {
    const float* z   = (const float*)d_in[0];   // (64,64,32,32) f32 NCHW
    const float* cb  = (const float*)d_in[1];   // (1024,64) f32
    const int*   flg = (const int*)d_in[3];     // flg_train

    float* out = (float*)d_out;
    char*  ws  = (char*)d_ws;

    ushort* cbf       = (ushort*)(ws + WS_CBF);
    float*  c2h       = (float*)(ws + WS_C2H);
    int*    hist      = (int*)(ws + WS_HIST);
    float*  loss_part = (float*)(ws + WS_LOSS);

    prep_kernel<<<68, 256, 0, stream>>>(cb, cbf, c2h, hist, loss_part);
    vq_kernel<<<1024, 256, 0, stream>>>(z, cb, cbf, c2h, out, loss_part, hist);
    finalize_kernel<<<1, 1024, 0, stream>>>(hist, loss_part, flg, out);
}